// Round 7
// baseline (880.871 us; speedup 1.0000x reference)
//
#include <hip/hip_runtime.h>
#include <hip/hip_bf16.h>
#include <cstdint>

// MoE top-2: B=4 S=2048 D=1024 F=4096 E=8, all fp32 in/out.
// Round 7: v6 loop structure (single-buffer, compiler-managed barriers,
// global_load_lds), 256x256 tiles (staged bytes -33%), XCD-aligned grid
// (x=mb, gridX=72==0 mod 8 -> all nblk blocks of an mb share one XCD's L2
// for the gathered-A panel). gemm2: BN=256, K-split x2.
//
// ws layout (full path, ~298 MB):
//   [0,32)        cnt[8]
//   [64,100)      hoff[9]
//   [104,108)     nmb
//   [128,256)     zpage (zeros)
//   [256,896)     mbe[160]   expert id per global mblock (granule 256)
//   [896,1536)    mbb[160]   local mblk per global mblock
//   [1536,67072)  psum[2048][8]
//   [67072,..)    list[8][8192]
//   [329216,..)   coef[8][8192]
//   [1MB)         xbf   bf16 X (router)            16 MB
//   [18MB)        w1t   bf16 [e][f][d]             64 MB
//   [82MB)        w2t   bf16 [e][d][f]             64 MB
//   [146MB)       h     bf16, rows padded to 256  151 MB
// Fallback (ws < FULL_WS): round-1 reg-staged 128^2 kernels, h at 1MB.

#define N_TOK 8192
#define D_DIM 1024
#define F_DIM 4096
#define N_EXP 8
#define MB_MAX 72

#define CNT_OFF   0u
#define HOFF_OFF  64u
#define NMB_OFF   104u
#define ZPG_OFF   128u
#define MBE_OFF   256u
#define MBB_OFF   896u
#define PSUM_OFF  1536u
#define LIST_OFF  67072u
#define COEF_OFF  329216u
#define H1_OFF    1048576ull          // fallback h
#define XBF_OFF   1048576ull
#define W1T_OFF   18874368ull
#define W2T_OFF   (W1T_OFF + 67108864ull)
#define H2_OFF    (W2T_OFF + 67108864ull)
#define FULL_WS   (H2_OFF + 18432ull * 4096ull * 2ull)

typedef __attribute__((ext_vector_type(8))) short short8;
typedef __attribute__((ext_vector_type(4))) float f32x4;
typedef __attribute__((ext_vector_type(4))) float float4v;
typedef __attribute__((ext_vector_type(2))) unsigned int u32x2;

__device__ __forceinline__ unsigned short f2bf(float x) {
  unsigned int u = __float_as_uint(x);
  unsigned int r = (u + 0x7fffu + ((u >> 16) & 1u)) >> 16;
  return (unsigned short)r;
}

__device__ __forceinline__ void gload16(const void* g, void* l) {
  __builtin_amdgcn_global_load_lds(
      (const __attribute__((address_space(1))) void*)g,
      (__attribute__((address_space(3))) void*)l, 16, 0, 0);
}

// ---------------------------------------------------------------- router ----
__global__ void router_kernel(const float* __restrict__ x,
                              const float* __restrict__ gw,
                              int* __restrict__ cnt, int* __restrict__ list,
                              float* __restrict__ coef,
                              float* __restrict__ psum,
                              unsigned short* __restrict__ xbf) {
  const int wave = threadIdx.x >> 6;
  const int lane = threadIdx.x & 63;
  const int t = blockIdx.x * 4 + wave;

  __shared__ float bps[N_EXP];
  if (threadIdx.x < N_EXP) bps[threadIdx.x] = 0.f;
  __syncthreads();

  float lg[8] = {0.f, 0.f, 0.f, 0.f, 0.f, 0.f, 0.f, 0.f};
  const float* xr = x + (size_t)t * D_DIM;
  unsigned short* xbr = xbf + (size_t)t * D_DIM;
#pragma unroll
  for (int i = 0; i < 16; ++i) {
    int d = lane + i * 64;
    float xv = xr[d];
    xbr[d] = f2bf(xv);
    float4v w0 = *(const float4v*)(gw + d * 8);
    float4v w1 = *(const float4v*)(gw + d * 8 + 4);
    lg[0] = fmaf(xv, w0.x, lg[0]); lg[1] = fmaf(xv, w0.y, lg[1]);
    lg[2] = fmaf(xv, w0.z, lg[2]); lg[3] = fmaf(xv, w0.w, lg[3]);
    lg[4] = fmaf(xv, w1.x, lg[4]); lg[5] = fmaf(xv, w1.y, lg[5]);
    lg[6] = fmaf(xv, w1.z, lg[6]); lg[7] = fmaf(xv, w1.w, lg[7]);
  }
#pragma unroll
  for (int m = 32; m; m >>= 1) {
#pragma unroll
    for (int e = 0; e < 8; ++e) lg[e] += __shfl_xor(lg[e], m);
  }

  if (lane == 0) {
    float mx = lg[0];
#pragma unroll
    for (int e = 1; e < 8; ++e) mx = fmaxf(mx, lg[e]);
    float p[8], s = 0.f;
#pragma unroll
    for (int e = 0; e < 8; ++e) { p[e] = expf(lg[e] - mx); s += p[e]; }
    float inv = 1.f / s;
#pragma unroll
    for (int e = 0; e < 8; ++e) atomicAdd(&bps[e], p[e] * inv);

    int i0 = 0;
#pragma unroll
    for (int e = 1; e < 8; ++e) if (lg[e] > lg[i0]) i0 = e;
    int i1 = (i0 == 0) ? 1 : 0;
#pragma unroll
    for (int e = 0; e < 8; ++e) if (e != i1 && e != i0 && lg[e] > lg[i1]) i1 = e;
    float p0 = 1.f / (1.f + expf(lg[i1] - lg[i0]));
    float p1 = 1.f - p0;
    int s0 = atomicAdd(&cnt[i0], 1);
    list[i0 * N_TOK + s0] = t; coef[i0 * N_TOK + s0] = p0;
    int s1 = atomicAdd(&cnt[i1], 1);
    list[i1 * N_TOK + s1] = t; coef[i1 * N_TOK + s1] = p1;
  }
  __syncthreads();
  if (threadIdx.x < 8) psum[blockIdx.x * 8 + threadIdx.x] = bps[threadIdx.x];
}

// ---------------------------------------------------------------- prefix ----
__global__ void prefix_kernel(const int* __restrict__ cnt, int* __restrict__ hoff,
                              int* __restrict__ mbe, int* __restrict__ mbb,
                              int* __restrict__ nmb, int g) {
  if (threadIdx.x == 0) {
    int o = 0, gmb = 0;
    for (int e = 0; e < 8; ++e) {
      hoff[e] = o;
      int nb = (cnt[e] + g - 1) / g;
      for (int m = 0; m < nb; ++m) { mbe[gmb] = e; mbb[gmb] = m; ++gmb; }
      o += nb * g;
    }
    hoff[8] = o;
    *nmb = gmb;
  }
}

// -------------------------------------------------------------------- KL ----
__global__ void kl_kernel(const float* __restrict__ psum, float* __restrict__ out_kl) {
  __shared__ float s[8];
  if (threadIdx.x < 8) s[threadIdx.x] = 0.f;
  __syncthreads();
  float loc[8] = {0.f, 0.f, 0.f, 0.f, 0.f, 0.f, 0.f, 0.f};
  for (int r = threadIdx.x; r < 2048; r += 256) {
#pragma unroll
    for (int e = 0; e < 8; ++e) loc[e] += psum[r * 8 + e];
  }
#pragma unroll
  for (int e = 0; e < 8; ++e) atomicAdd(&s[e], loc[e]);
  __syncthreads();
  if (threadIdx.x == 0) {
    float kl = 0.f;
#pragma unroll
    for (int e = 0; e < 8; ++e) {
      float mean = s[e] / 8192.f;
      kl += (logf(0.125f) - logf(mean));
    }
    out_kl[0] = kl * (0.125f * 0.125f);
  }
}

// ------------------------------------------------------------------ prep ----
// w: [E][K][N] f32 -> wt: [E][N][K] bf16, 64x64 LDS tiles
__global__ __launch_bounds__(256) void wtrans_kernel(
    const float* __restrict__ w, unsigned short* __restrict__ wt, int K, int N) {
  const int e = blockIdx.z;
  const int n0 = blockIdx.x * 64, k0 = blockIdx.y * 64;
  __shared__ float t[64][65];
  const float* we = w + (size_t)e * K * N;
  const int nl = threadIdx.x & 63;
  const int kl4 = threadIdx.x >> 6;
#pragma unroll
  for (int r = 0; r < 16; ++r) {
    int kl = r * 4 + kl4;
    t[kl][nl] = we[(size_t)(k0 + kl) * N + n0 + nl];
  }
  __syncthreads();
  unsigned short* wte = wt + (size_t)e * K * N;
  const int kp = (threadIdx.x & 31) * 2;
  const int nl8 = threadIdx.x >> 5;
#pragma unroll
  for (int r = 0; r < 8; ++r) {
    int n = r * 8 + nl8;
    unsigned int pk = (unsigned int)f2bf(t[kp][n]) |
                      ((unsigned int)f2bf(t[kp + 1][n]) << 16);
    *(unsigned int*)(wte + (size_t)(n0 + n) * K + k0 + kp) = pk;
  }
}

// ------------------------------------------------------- MFMA frag loader ---
// LDS tiles [rows][64 bf16] (128 B rows), swizzled read: byte ^= (row&7)<<4.
__device__ __forceinline__ short8 ld_frag(const unsigned short* base, int row_base,
                                          int k_base, int lane) {
  int row = row_base + (lane & 15);
  int byte = (row * 128 + (k_base + ((lane >> 4) << 3)) * 2) ^ ((row & 7) << 4);
  return *(const short8*)((const char*)base + byte);
}

// ------------------------------------------------------------- GEMM1 (v7) ---
// h[rows,4096] = silu( Xg[rows,1024] @ W1[e] ), BM=BN=256, BK=64, 8 waves,
// single-buffer loop. Grid (x=mb[72], y=nblk[16]) -> id%8 = mb%8 (XCD-local A).
__global__ __launch_bounds__(512, 2) void gemm1_v7(
    const unsigned short* __restrict__ xbf, const unsigned short* __restrict__ w1t,
    const int* __restrict__ cnt, const int* __restrict__ hoff,
    const int* __restrict__ mbe, const int* __restrict__ mbb,
    const int* __restrict__ nmb,
    const int* __restrict__ list, const unsigned short* __restrict__ zpage,
    unsigned short* __restrict__ h) {
  const int mb = blockIdx.x;
  if (mb >= *nmb) return;
  const int e = mbe[mb], mblk = mbb[mb], nblk = blockIdx.y;
  const int c = cnt[e];
  const int tid = threadIdx.x, lane = tid & 63, wave = tid >> 6;
  const int wm = (wave >> 2) * 128, wn = (wave & 3) * 64;   // 2(M) x 4(N)

  __shared__ unsigned short As[256 * 64];   // 32 KB
  __shared__ unsigned short Bs[256 * 64];   // 32 KB

  const int rowb = tid >> 3;                          // [0,64)
  const int sw = (((tid & 7) ^ (rowb & 7)) << 4);     // pre-swizzle byte
  const char* asrc[4]; int astep[4];
  const char* bsrc[4];
#pragma unroll
  for (int i = 0; i < 4; ++i) {
    int row = i * 64 + rowb;
    int slot = mblk * 256 + row;
    if (slot < c) {
      int tok = list[e * N_TOK + slot];
      asrc[i] = (const char*)(xbf + (size_t)tok * D_DIM) + sw;
      astep[i] = 128;
    } else {
      asrc[i] = (const char*)zpage + sw;
      astep[i] = 0;
    }
    bsrc[i] = (const char*)(w1t + ((size_t)e * F_DIM + nblk * 256 + row) * D_DIM) + sw;
  }

  f32x4 acc[8][4];
#pragma unroll
  for (int i = 0; i < 8; ++i)
#pragma unroll
    for (int j = 0; j < 4; ++j) acc[i][j] = f32x4{0.f, 0.f, 0.f, 0.f};

  for (int kc = 0; kc < 16; ++kc) {
    __syncthreads();
#pragma unroll
    for (int i = 0; i < 4; ++i) {
      gload16(asrc[i], (char*)As + i * 8192 + tid * 16);
      asrc[i] += astep[i];
      gload16(bsrc[i], (char*)Bs + i * 8192 + tid * 16);
      bsrc[i] += 128;
    }
    __syncthreads();
#pragma unroll
    for (int ks = 0; ks < 2; ++ks) {
      short8 af[8], bb[4];
#pragma unroll
      for (int mf = 0; mf < 8; ++mf) af[mf] = ld_frag(As, wm + mf * 16, ks * 32, lane);
#pragma unroll
      for (int nf = 0; nf < 4; ++nf) bb[nf] = ld_frag(Bs, wn + nf * 16, ks * 32, lane);
#pragma unroll
      for (int mf = 0; mf < 8; ++mf)
#pragma unroll
        for (int nf = 0; nf < 4; ++nf)
          acc[mf][nf] = __builtin_amdgcn_mfma_f32_16x16x32_bf16(
              af[mf], bb[nf], acc[mf][nf], 0, 0, 0);
    }
  }

  const int hbase = hoff[e] + mblk * 256;
#pragma unroll
  for (int mf = 0; mf < 8; ++mf)
#pragma unroll
    for (int nf = 0; nf < 4; ++nf)
#pragma unroll
      for (int r = 0; r < 4; ++r) {
        float v = acc[mf][nf][r];
        v = v / (1.f + __expf(-v));
        int row = wm + mf * 16 + ((lane >> 4) << 2) + r;
        int col = nblk * 256 + wn + nf * 16 + (lane & 15);
        h[(size_t)(hbase + row) * F_DIM + col] = f2bf(v);
      }
}

// ------------------------------------------------------------- GEMM2 (v7) ---
// out[tok,:] += coef * ( h @ W2[e] ), BM=BN=256, K-split x2.
// Grid (x=mb[72], y=8): nblk = y&3, kh = y>>2.
__global__ __launch_bounds__(512, 2) void gemm2_v7(
    const unsigned short* __restrict__ h, const unsigned short* __restrict__ w2t,
    const int* __restrict__ cnt, const int* __restrict__ hoff,
    const int* __restrict__ mbe, const int* __restrict__ mbb,
    const int* __restrict__ nmb,
    const int* __restrict__ list, const float* __restrict__ coef,
    float* __restrict__ out) {
  const int mb = blockIdx.x;
  if (mb >= *nmb) return;
  const int e = mbe[mb], mblk = mbb[mb];
  const int nblk = blockIdx.y & 3;
  const int kofs = (blockIdx.y >> 2) * 2048;          // bf16 elements
  const int c = cnt[e];
  const int tid = threadIdx.x, lane = tid & 63, wave = tid >> 6;
  const int wm = (wave >> 2) * 128, wn = (wave & 3) * 64;

  __shared__ unsigned short As[256 * 64];
  __shared__ unsigned short Bs[256 * 64];

  const int rowb = tid >> 3;
  const int sw = (((tid & 7) ^ (rowb & 7)) << 4);
  const int hbase = hoff[e] + mblk * 256;
  const char* asrc[4];
  const char* bsrc[4];
#pragma unroll
  for (int i = 0; i < 4; ++i) {
    int row = i * 64 + rowb;
    asrc[i] = (const char*)(h + (size_t)(hbase + row) * F_DIM + kofs) + sw;
    bsrc[i] = (const char*)(w2t + ((size_t)e * D_DIM + nblk * 256 + row) * F_DIM + kofs) + sw;
  }

  f32x4 acc[8][4];
#pragma unroll
  for (int i = 0; i < 8; ++i)
#pragma unroll
    for (int j = 0; j < 4; ++j) acc[i][j] = f32x4{0.f, 0.f, 0.f, 0.f};

  for (int kc = 0; kc < 32; ++kc) {
    __syncthreads();
#pragma unroll
    for (int i = 0; i < 4; ++i) {
      gload16(asrc[i], (char*)As + i * 8192 + tid * 16);
      asrc[i] += 128;
      gload16(bsrc[i], (char*)Bs + i * 8192 + tid * 16);
      bsrc[i] += 128;
    }
    __syncthreads();
#pragma unroll
    for (int ks = 0; ks < 2; ++ks) {
      short8 af[8], bb[4];
#pragma unroll
      for (int mf = 0; mf < 8; ++mf) af[mf] = ld_frag(As, wm + mf * 16, ks * 32, lane);
#pragma unroll
      for (int nf = 0; nf < 4; ++nf) bb[nf] = ld_frag(Bs, wn + nf * 16, ks * 32, lane);
#pragma unroll
      for (int mf = 0; mf < 8; ++mf)
#pragma unroll
        for (int nf = 0; nf < 4; ++nf)
          acc[mf][nf] = __builtin_amdgcn_mfma_f32_16x16x32_bf16(
              af[mf], bb[nf], acc[mf][nf], 0, 0, 0);
    }
  }

#pragma unroll
  for (int mf = 0; mf < 8; ++mf) {
#pragma unroll
    for (int r = 0; r < 4; ++r) {
      int slot = mblk * 256 + wm + mf * 16 + ((lane >> 4) << 2) + r;
      if (slot < c) {
        int tok = list[e * N_TOK + slot];
        float cf = coef[e * N_TOK + slot];
#pragma unroll
        for (int nf = 0; nf < 4; ++nf) {
          int col = nblk * 256 + wn + nf * 16 + (lane & 15);
          unsafeAtomicAdd(&out[(size_t)tok * D_DIM + col], cf * acc[mf][nf][r]);
        }
      }
    }
  }
}

// ------------------------------------------------- fallback (round-1) GEMMs --
__global__ __launch_bounds__(256) void gemm1_v1(
    const float* __restrict__ x, const float* __restrict__ w1,
    const int* __restrict__ cnt, const int* __restrict__ hoff,
    const int* __restrict__ list, unsigned short* __restrict__ h) {
  const int e = blockIdx.z, mblk = blockIdx.y, nblk = blockIdx.x;
  const int c = cnt[e];
  if (mblk * 128 >= c) return;
  const int tid = threadIdx.x, lane = tid & 63, wave = tid >> 6;
  const int wm = (wave >> 1) * 64, wn = (wave & 1) * 64;

  __shared__ unsigned short At[128 * 64];
  __shared__ unsigned short Bt[128 * 64];
  __shared__ int toks[128];
  if (tid < 128) {
    int slot = mblk * 128 + tid;
    toks[tid] = (slot < c) ? list[e * N_TOK + slot] : -1;
  }
  __syncthreads();

  f32x4 acc[4][4];
#pragma unroll
  for (int i = 0; i < 4; ++i)
#pragma unroll
    for (int j = 0; j < 4; ++j) acc[i][j] = f32x4{0.f, 0.f, 0.f, 0.f};

  const float* w1e = w1 + (size_t)e * D_DIM * F_DIM;
  for (int kc = 0; kc < 16; ++kc) {
    __syncthreads();
#pragma unroll
    for (int it = 0; it < 8; ++it) {
      int lin = it * 256 + tid;
      int row = lin >> 4, c4 = lin & 15;
      int tok = toks[row];
      unsigned int lo = 0u, hi = 0u;
      if (tok >= 0) {
        float4v f = *(const float4v*)(x + (size_t)tok * D_DIM + kc * 64 + c4 * 4);
        lo = (unsigned int)f2bf(f.x) | ((unsigned int)f2bf(f.y) << 16);
        hi = (unsigned int)f2bf(f.z) | ((unsigned int)f2bf(f.w) << 16);
      }
      int byte = (row * 128 + c4 * 8) ^ ((row & 7) << 4);
      *(u32x2*)((char*)At + byte) = u32x2{lo, hi};
    }
#pragma unroll
    for (int it = 0; it < 16; ++it) {
      int lin = it * 256 + tid;
      int f_loc = lin & 127, dp = lin >> 7;
      int d = kc * 64 + dp * 2;
      const float* src = w1e + (size_t)d * F_DIM + nblk * 128 + f_loc;
      unsigned int pk = (unsigned int)f2bf(src[0]) |
                        ((unsigned int)f2bf(src[F_DIM]) << 16);
      int byte = (f_loc * 128 + dp * 4) ^ ((f_loc & 7) << 4);
      *(unsigned int*)((char*)Bt + byte) = pk;
    }
    __syncthreads();
#pragma unroll
    for (int ks = 0; ks < 2; ++ks) {
      short8 af[4], bb[4];
#pragma unroll
      for (int mf = 0; mf < 4; ++mf) af[mf] = ld_frag(At, wm + mf * 16, ks * 32, lane);
#pragma unroll
      for (int nf = 0; nf < 4; ++nf) bb[nf] = ld_frag(Bt, wn + nf * 16, ks * 32, lane);
#pragma unroll
      for (int mf = 0; mf < 4; ++mf)
#pragma unroll
        for (int nf = 0; nf < 4; ++nf)
          acc[mf][nf] = __builtin_amdgcn_mfma_f32_16x16x32_bf16(
              af[mf], bb[nf], acc[mf][nf], 0, 0, 0);
    }
  }

  const int hbase = hoff[e] + mblk * 128;
#pragma unroll
  for (int mf = 0; mf < 4; ++mf)
#pragma unroll
    for (int nf = 0; nf < 4; ++nf)
#pragma unroll
      for (int r = 0; r < 4; ++r) {
        float v = acc[mf][nf][r];
        v = v / (1.f + __expf(-v));
        int row = wm + mf * 16 + ((lane >> 4) << 2) + r;
        int col = nblk * 128 + wn + nf * 16 + (lane & 15);
        h[(size_t)(hbase + row) * F_DIM + col] = f2bf(v);
      }
}

__global__ __launch_bounds__(256) void gemm2_v1(
    const unsigned short* __restrict__ h, const float* __restrict__ w2,
    const int* __restrict__ cnt, const int* __restrict__ hoff,
    const int* __restrict__ list, const float* __restrict__ coef,
    float* __restrict__ out) {
  const int e = blockIdx.z, mblk = blockIdx.y, nblk = blockIdx.x;
  const int c = cnt[e];
  if (mblk * 128 >= c) return;
  const int tid = threadIdx.x, lane = tid & 63, wave = tid >> 6;
  const int wm = (wave >> 1) * 64, wn = (wave & 1) * 64;

  __shared__ unsigned short At[128 * 64];
  __shared__ unsigned short Bt[128 * 64];

  f32x4 acc[4][4];
#pragma unroll
  for (int i = 0; i < 4; ++i)
#pragma unroll
    for (int j = 0; j < 4; ++j) acc[i][j] = f32x4{0.f, 0.f, 0.f, 0.f};

  const int hbase = hoff[e] + mblk * 128;
  const float* w2e = w2 + (size_t)e * F_DIM * D_DIM;
  for (int kc = 0; kc < 64; ++kc) {
    __syncthreads();
#pragma unroll
    for (int it = 0; it < 8; ++it) {
      int lin = it * 256 + tid;
      int row = lin >> 4, c4 = lin & 15;
      u32x2 v = *(const u32x2*)(h + (size_t)(hbase + row) * F_DIM + kc * 64 + c4 * 4);
      int byte = (row * 128 + c4 * 8) ^ ((row & 7) << 4);
      *(u32x2*)((char*)At + byte) = v;
    }
#pragma unroll
    for (int it = 0; it < 16; ++it) {
      int lin = it * 256 + tid;
      int dcol = lin & 127, kp = lin >> 7;
      int k = kc * 64 + kp * 2;
      const float* src = w2e + (size_t)k * D_DIM + nblk * 128 + dcol;
      unsigned int pk = (unsigned int)f2bf(src[0]) |
                        ((unsigned int)f2bf(src[D_DIM]) << 16);
      int byte = (dcol * 128 + kp * 4) ^ ((dcol & 7) << 4);
      *(unsigned int*)((char*)Bt + byte) = pk;
    }
    __syncthreads();
#pragma unroll
    for (int ks = 0; ks < 2; ++ks) {
      short8 af[4], bb[4];
#pragma unroll
      for (int mf = 0; mf < 4; ++mf) af[mf] = ld_frag(At, wm + mf * 16, ks * 32, lane);
#pragma unroll
      for (int nf = 0; nf < 4; ++nf) bb[nf] = ld_frag(Bt, wn + nf * 16, ks * 32, lane);
#pragma unroll
      for (int mf = 0; mf < 4; ++mf)
#pragma unroll
        for (int nf = 0; nf < 4; ++nf)
          acc[mf][nf] = __builtin_amdgcn_mfma_f32_16x16x32_bf16(
              af[mf], bb[nf], acc[mf][nf], 0, 0, 0);
    }
  }

#pragma unroll
  for (int mf = 0; mf < 4; ++mf) {
#pragma unroll
    for (int r = 0; r < 4; ++r) {
      int slot = mblk * 128 + wm + mf * 16 + ((lane >> 4) << 2) + r;
      if (slot < c) {
        int tok = list[e * N_TOK + slot];
        float cf = coef[e * N_TOK + slot];
#pragma unroll
        for (int nf = 0; nf < 4; ++nf) {
          int col = nblk * 128 + wn + nf * 16 + (lane & 15);
          unsafeAtomicAdd(&out[(size_t)tok * D_DIM + col], cf * acc[mf][nf][r]);
        }
      }
    }
  }
}

// ------------------------------------------------------------------ launch --
extern "C" void kernel_launch(void* const* d_in, const int* in_sizes, int n_in,
                              void* d_out, int out_size, void* d_ws, size_t ws_size,
                              hipStream_t stream) {
  const float* x = (const float*)d_in[0];
  const float* gw = (const float*)d_in[1];
  const float* w1 = (const float*)d_in[2];
  const float* w2 = (const float*)d_in[3];
  float* out = (float*)d_out;
  char* ws = (char*)d_ws;

  int* cnt = (int*)(ws + CNT_OFF);
  int* hoff = (int*)(ws + HOFF_OFF);
  int* nmb = (int*)(ws + NMB_OFF);
  int* mbe = (int*)(ws + MBE_OFF);
  int* mbb = (int*)(ws + MBB_OFF);
  float* psum = (float*)(ws + PSUM_OFF);
  int* list = (int*)(ws + LIST_OFF);
  float* coef = (float*)(ws + COEF_OFF);
  unsigned short* xbf = (unsigned short*)(ws + XBF_OFF);

  const bool full = (ws_size >= FULL_WS);

  hipMemsetAsync(d_ws, 0, PSUM_OFF + 2048 * 8 * 4, stream);
  hipMemsetAsync(d_out, 0, (size_t)out_size * 4, stream);

  router_kernel<<<2048, 256, 0, stream>>>(x, gw, cnt, list, coef, psum, xbf);
  prefix_kernel<<<1, 64, 0, stream>>>(cnt, hoff, mbe, mbb, nmb, full ? 256 : 128);
  kl_kernel<<<1, 256, 0, stream>>>(psum, out + 8388608);

  if (full) {
    unsigned short* w1t = (unsigned short*)(ws + W1T_OFF);
    unsigned short* w2t = (unsigned short*)(ws + W2T_OFF);
    unsigned short* h = (unsigned short*)(ws + H2_OFF);
    const unsigned short* zpage = (const unsigned short*)(ws + ZPG_OFF);

    wtrans_kernel<<<dim3(64, 16, 8), 256, 0, stream>>>(w1, w1t, 1024, 4096);
    wtrans_kernel<<<dim3(16, 64, 8), 256, 0, stream>>>(w2, w2t, 4096, 1024);
    gemm1_v7<<<dim3(MB_MAX, 16), 512, 0, stream>>>(xbf, w1t, cnt, hoff, mbe, mbb,
                                                   nmb, list, zpage, h);
    gemm2_v7<<<dim3(MB_MAX, 8), 512, 0, stream>>>(h, w2t, cnt, hoff, mbe, mbb,
                                                  nmb, list, coef, out);
  } else {
    unsigned short* h = (unsigned short*)(ws + H1_OFF);
    gemm1_v1<<<dim3(32, 64, 8), 256, 0, stream>>>(x, w1, cnt, hoff, list, h);
    gemm2_v1<<<dim3(8, 64, 8), 256, 0, stream>>>(h, w2, cnt, hoff, list, coef, out);
  }
}

// Round 8
// 848.926 us; speedup vs baseline: 1.0376x; 1.0376x over previous
//
#include <hip/hip_runtime.h>
#include <hip/hip_bf16.h>
#include <cstdint>

// MoE top-2: B=4 S=2048 D=1024 F=4096 E=8, all fp32 in/out.
// Round 8: doc-recipe 2-phase prefetch (T3 minimum): STAGE(next buf) ->
// compute(cur) -> __syncthreads() [vmcnt(0)+barrier] per K-iter, 256^2 tile,
// double-buffered 128KB LDS, buffer select via runtime byte offset (no
// control-flow diamond -> no spill), chunked frag loads, setprio on MFMA
// clusters, compact XCD-aligned mb-grid, gemm2 K-split x2.
//
// ws layout (full path, ~298 MB):
//   [0,32)        cnt[8]
//   [64,100)      hoff[9]
//   [104,108)     nmb
//   [128,256)     zpage (zeros)
//   [256,896)     mbe[160]   expert id per global mblock (granule 256)
//   [896,1536)    mbb[160]   local mblk per global mblock
//   [1536,67072)  psum[2048][8]
//   [67072,..)    list[8][8192]
//   [329216,..)   coef[8][8192]
//   [1MB)         xbf   bf16 X (router)            16 MB
//   [18MB)        w1t   bf16 [e][f][d]             64 MB
//   [82MB)        w2t   bf16 [e][d][f]             64 MB
//   [146MB)       h     bf16, rows padded to 256  151 MB
// Fallback (ws < FULL_WS): round-1 reg-staged 128^2 kernels, h at 1MB.

#define N_TOK 8192
#define D_DIM 1024
#define F_DIM 4096
#define N_EXP 8
#define MB_MAX 72

#define CNT_OFF   0u
#define HOFF_OFF  64u
#define NMB_OFF   104u
#define ZPG_OFF   128u
#define MBE_OFF   256u
#define MBB_OFF   896u
#define PSUM_OFF  1536u
#define LIST_OFF  67072u
#define COEF_OFF  329216u
#define H1_OFF    1048576ull          // fallback h
#define XBF_OFF   1048576ull
#define W1T_OFF   18874368ull
#define W2T_OFF   (W1T_OFF + 67108864ull)
#define H2_OFF    (W2T_OFF + 67108864ull)
#define FULL_WS   (H2_OFF + 18432ull * 4096ull * 2ull)

typedef __attribute__((ext_vector_type(8))) short short8;
typedef __attribute__((ext_vector_type(4))) float f32x4;
typedef __attribute__((ext_vector_type(4))) float float4v;
typedef __attribute__((ext_vector_type(2))) unsigned int u32x2;

__device__ __forceinline__ unsigned short f2bf(float x) {
  unsigned int u = __float_as_uint(x);
  unsigned int r = (u + 0x7fffu + ((u >> 16) & 1u)) >> 16;
  return (unsigned short)r;
}

__device__ __forceinline__ void gload16(const void* g, void* l) {
  __builtin_amdgcn_global_load_lds(
      (const __attribute__((address_space(1))) void*)g,
      (__attribute__((address_space(3))) void*)l, 16, 0, 0);
}

// ---------------------------------------------------------------- router ----
__global__ void router_kernel(const float* __restrict__ x,
                              const float* __restrict__ gw,
                              int* __restrict__ cnt, int* __restrict__ list,
                              float* __restrict__ coef,
                              float* __restrict__ psum,
                              unsigned short* __restrict__ xbf) {
  const int wave = threadIdx.x >> 6;
  const int lane = threadIdx.x & 63;
  const int t = blockIdx.x * 4 + wave;

  __shared__ float bps[N_EXP];
  if (threadIdx.x < N_EXP) bps[threadIdx.x] = 0.f;
  __syncthreads();

  float lg[8] = {0.f, 0.f, 0.f, 0.f, 0.f, 0.f, 0.f, 0.f};
  const float* xr = x + (size_t)t * D_DIM;
  unsigned short* xbr = xbf + (size_t)t * D_DIM;
#pragma unroll
  for (int i = 0; i < 16; ++i) {
    int d = lane + i * 64;
    float xv = xr[d];
    xbr[d] = f2bf(xv);
    float4v w0 = *(const float4v*)(gw + d * 8);
    float4v w1 = *(const float4v*)(gw + d * 8 + 4);
    lg[0] = fmaf(xv, w0.x, lg[0]); lg[1] = fmaf(xv, w0.y, lg[1]);
    lg[2] = fmaf(xv, w0.z, lg[2]); lg[3] = fmaf(xv, w0.w, lg[3]);
    lg[4] = fmaf(xv, w1.x, lg[4]); lg[5] = fmaf(xv, w1.y, lg[5]);
    lg[6] = fmaf(xv, w1.z, lg[6]); lg[7] = fmaf(xv, w1.w, lg[7]);
  }
#pragma unroll
  for (int m = 32; m; m >>= 1) {
#pragma unroll
    for (int e = 0; e < 8; ++e) lg[e] += __shfl_xor(lg[e], m);
  }

  if (lane == 0) {
    float mx = lg[0];
#pragma unroll
    for (int e = 1; e < 8; ++e) mx = fmaxf(mx, lg[e]);
    float p[8], s = 0.f;
#pragma unroll
    for (int e = 0; e < 8; ++e) { p[e] = expf(lg[e] - mx); s += p[e]; }
    float inv = 1.f / s;
#pragma unroll
    for (int e = 0; e < 8; ++e) atomicAdd(&bps[e], p[e] * inv);

    int i0 = 0;
#pragma unroll
    for (int e = 1; e < 8; ++e) if (lg[e] > lg[i0]) i0 = e;
    int i1 = (i0 == 0) ? 1 : 0;
#pragma unroll
    for (int e = 0; e < 8; ++e) if (e != i1 && e != i0 && lg[e] > lg[i1]) i1 = e;
    float p0 = 1.f / (1.f + expf(lg[i1] - lg[i0]));
    float p1 = 1.f - p0;
    int s0 = atomicAdd(&cnt[i0], 1);
    list[i0 * N_TOK + s0] = t; coef[i0 * N_TOK + s0] = p0;
    int s1 = atomicAdd(&cnt[i1], 1);
    list[i1 * N_TOK + s1] = t; coef[i1 * N_TOK + s1] = p1;
  }
  __syncthreads();
  if (threadIdx.x < 8) psum[blockIdx.x * 8 + threadIdx.x] = bps[threadIdx.x];
}

// ---------------------------------------------------------------- prefix ----
__global__ void prefix_kernel(const int* __restrict__ cnt, int* __restrict__ hoff,
                              int* __restrict__ mbe, int* __restrict__ mbb,
                              int* __restrict__ nmb, int g) {
  if (threadIdx.x == 0) {
    int o = 0, gmb = 0;
    for (int e = 0; e < 8; ++e) {
      hoff[e] = o;
      int nb = (cnt[e] + g - 1) / g;
      for (int m = 0; m < nb; ++m) { mbe[gmb] = e; mbb[gmb] = m; ++gmb; }
      o += nb * g;
    }
    hoff[8] = o;
    *nmb = gmb;
  }
}

// -------------------------------------------------------------------- KL ----
__global__ void kl_kernel(const float* __restrict__ psum, float* __restrict__ out_kl) {
  __shared__ float s[8];
  if (threadIdx.x < 8) s[threadIdx.x] = 0.f;
  __syncthreads();
  float loc[8] = {0.f, 0.f, 0.f, 0.f, 0.f, 0.f, 0.f, 0.f};
  for (int r = threadIdx.x; r < 2048; r += 256) {
#pragma unroll
    for (int e = 0; e < 8; ++e) loc[e] += psum[r * 8 + e];
  }
#pragma unroll
  for (int e = 0; e < 8; ++e) atomicAdd(&s[e], loc[e]);
  __syncthreads();
  if (threadIdx.x == 0) {
    float kl = 0.f;
#pragma unroll
    for (int e = 0; e < 8; ++e) {
      float mean = s[e] / 8192.f;
      kl += (logf(0.125f) - logf(mean));
    }
    out_kl[0] = kl * (0.125f * 0.125f);
  }
}

// ------------------------------------------------------------------ prep ----
// w: [E][K][N] f32 -> wt: [E][N][K] bf16, 64x64 LDS tiles
__global__ __launch_bounds__(256) void wtrans_kernel(
    const float* __restrict__ w, unsigned short* __restrict__ wt, int K, int N) {
  const int e = blockIdx.z;
  const int n0 = blockIdx.x * 64, k0 = blockIdx.y * 64;
  __shared__ float t[64][65];
  const float* we = w + (size_t)e * K * N;
  const int nl = threadIdx.x & 63;
  const int kl4 = threadIdx.x >> 6;
#pragma unroll
  for (int r = 0; r < 16; ++r) {
    int kl = r * 4 + kl4;
    t[kl][nl] = we[(size_t)(k0 + kl) * N + n0 + nl];
  }
  __syncthreads();
  unsigned short* wte = wt + (size_t)e * K * N;
  const int kp = (threadIdx.x & 31) * 2;
  const int nl8 = threadIdx.x >> 5;
#pragma unroll
  for (int r = 0; r < 8; ++r) {
    int n = r * 8 + nl8;
    unsigned int pk = (unsigned int)f2bf(t[kp][n]) |
                      ((unsigned int)f2bf(t[kp + 1][n]) << 16);
    *(unsigned int*)(wte + (size_t)(n0 + n) * K + k0 + kp) = pk;
  }
}

// ------------------------------------------------------- MFMA frag loader ---
// LDS tiles [rows][64 bf16] (128 B rows), swizzled read: byte ^= (row&7)<<4.
__device__ __forceinline__ short8 ld_frag(const unsigned short* base, int row_base,
                                          int k_base, int lane) {
  int row = row_base + (lane & 15);
  int byte = (row * 128 + (k_base + ((lane >> 4) << 3)) * 2) ^ ((row & 7) << 4);
  return *(const short8*)((const char*)base + byte);
}

// Stage a 256x64 tile pair into LDS at byte offset `dst_bo` (0 or 32768).
#define STAGE(dst_bo)                                                      \
  {                                                                        \
    char* la_ = (char*)As + (dst_bo) + tid * 16;                           \
    char* lb_ = (char*)Bs + (dst_bo) + tid * 16;                           \
    _Pragma("unroll") for (int i_ = 0; i_ < 4; ++i_) {                     \
      gload16(asrc[i_], la_ + i_ * 8192);                                  \
      gload16(bsrc[i_], lb_ + i_ * 8192);                                  \
      asrc[i_] += astep[i_];                                               \
      bsrc[i_] += 128;                                                     \
    }                                                                      \
  }

// Compute one K-tile from LDS byte offset `bo`. Chunked frag loads keep
// live registers low (bb[4] + af[4]); setprio wraps each 16-MFMA cluster.
#define COMPUTE(bo)                                                        \
  {                                                                        \
    const unsigned short* At_ = (const unsigned short*)((const char*)As + (bo)); \
    const unsigned short* Bt_ = (const unsigned short*)((const char*)Bs + (bo)); \
    _Pragma("unroll") for (int ks_ = 0; ks_ < 2; ++ks_) {                  \
      short8 bb[4];                                                        \
      _Pragma("unroll") for (int nf_ = 0; nf_ < 4; ++nf_)                  \
        bb[nf_] = ld_frag(Bt_, wn + nf_ * 16, ks_ * 32, lane);             \
      _Pragma("unroll") for (int mh_ = 0; mh_ < 2; ++mh_) {                \
        short8 af[4];                                                      \
        _Pragma("unroll") for (int m4_ = 0; m4_ < 4; ++m4_)                \
          af[m4_] = ld_frag(At_, wm + mh_ * 64 + m4_ * 16, ks_ * 32, lane);\
        __builtin_amdgcn_s_setprio(1);                                     \
        _Pragma("unroll") for (int m4_ = 0; m4_ < 4; ++m4_)                \
          _Pragma("unroll") for (int nf_ = 0; nf_ < 4; ++nf_)              \
            acc[mh_ * 4 + m4_][nf_] = __builtin_amdgcn_mfma_f32_16x16x32_bf16( \
                af[m4_], bb[nf_], acc[mh_ * 4 + m4_][nf_], 0, 0, 0);       \
        __builtin_amdgcn_s_setprio(0);                                     \
      }                                                                    \
    }                                                                      \
  }

// Doc-recipe 2-phase loop: STAGE(next) -> COMPUTE(cur) -> syncthreads
// (= vmcnt(0)+lgkmcnt(0)+barrier). Buffer select via runtime byte offset.
#define KLOOP2(NT)                                                         \
  {                                                                        \
    STAGE(0);                                                              \
    __syncthreads();                                                       \
    int bo = 0;                                                            \
    for (int t_ = 0; t_ < (NT) - 1; ++t_) {                                \
      STAGE(bo ^ 32768);                                                   \
      COMPUTE(bo);                                                         \
      __syncthreads();                                                     \
      bo ^= 32768;                                                         \
    }                                                                      \
    COMPUTE(bo);                                                           \
  }

// ------------------------------------------------------------- GEMM1 (v8) ---
// h[rows,4096] = silu( Xg[rows,1024] @ W1[e] ), 256^2, 2-phase dbuf.
// Grid (x=mb[72], y=nblk[16]); gridX%8==0 -> same-mb blocks share an XCD.
__global__ __launch_bounds__(512, 2) void gemm1_v8(
    const unsigned short* __restrict__ xbf, const unsigned short* __restrict__ w1t,
    const int* __restrict__ cnt, const int* __restrict__ hoff,
    const int* __restrict__ mbe, const int* __restrict__ mbb,
    const int* __restrict__ nmb,
    const int* __restrict__ list, const unsigned short* __restrict__ zpage,
    unsigned short* __restrict__ h) {
  const int mb = blockIdx.x;
  if (mb >= *nmb) return;
  const int e = mbe[mb], mblk = mbb[mb], nblk = blockIdx.y;
  const int c = cnt[e];
  const int tid = threadIdx.x, lane = tid & 63, wave = tid >> 6;
  const int wm = (wave >> 2) * 128, wn = (wave & 3) * 64;   // 2(M) x 4(N)

  __shared__ unsigned short As[2][16384];   // 64 KB
  __shared__ unsigned short Bs[2][16384];   // 64 KB

  const int rowb = tid >> 3;                          // [0,64)
  const int sw = (((tid & 7) ^ (rowb & 7)) << 4);     // pre-swizzle byte
  const char* asrc[4]; int astep[4];
  const char* bsrc[4];
#pragma unroll
  for (int i = 0; i < 4; ++i) {
    int row = i * 64 + rowb;
    int slot = mblk * 256 + row;
    if (slot < c) {
      int tok = list[e * N_TOK + slot];
      asrc[i] = (const char*)(xbf + (size_t)tok * D_DIM) + sw;
      astep[i] = 128;
    } else {
      asrc[i] = (const char*)zpage + sw;
      astep[i] = 0;
    }
    bsrc[i] = (const char*)(w1t + ((size_t)e * F_DIM + nblk * 256 + i * 64 + rowb) * D_DIM) + sw;
  }

  f32x4 acc[8][4];
#pragma unroll
  for (int i = 0; i < 8; ++i)
#pragma unroll
    for (int j = 0; j < 4; ++j) acc[i][j] = f32x4{0.f, 0.f, 0.f, 0.f};

  KLOOP2(16);

  const int hbase = hoff[e] + mblk * 256;
#pragma unroll
  for (int mf = 0; mf < 8; ++mf)
#pragma unroll
    for (int nf = 0; nf < 4; ++nf)
#pragma unroll
      for (int r = 0; r < 4; ++r) {
        float v = acc[mf][nf][r];
        v = v / (1.f + __expf(-v));
        int row = wm + mf * 16 + ((lane >> 4) << 2) + r;
        int col = nblk * 256 + wn + nf * 16 + (lane & 15);
        h[(size_t)(hbase + row) * F_DIM + col] = f2bf(v);
      }
}

// ------------------------------------------------------------- GEMM2 (v8) ---
// out[tok,:] += coef * ( h @ W2[e] ), 256^2, 2-phase dbuf, K-split x2.
// Grid (x=mb[72], y=8): nblk = y&3, kh = y>>2.
__global__ __launch_bounds__(512, 2) void gemm2_v8(
    const unsigned short* __restrict__ h, const unsigned short* __restrict__ w2t,
    const int* __restrict__ cnt, const int* __restrict__ hoff,
    const int* __restrict__ mbe, const int* __restrict__ mbb,
    const int* __restrict__ nmb,
    const int* __restrict__ list, const float* __restrict__ coef,
    float* __restrict__ out) {
  const int mb = blockIdx.x;
  if (mb >= *nmb) return;
  const int e = mbe[mb], mblk = mbb[mb];
  const int nblk = blockIdx.y & 3;
  const int kofs = (blockIdx.y >> 2) * 2048;          // bf16 elements
  const int c = cnt[e];
  const int tid = threadIdx.x, lane = tid & 63, wave = tid >> 6;
  const int wm = (wave >> 2) * 128, wn = (wave & 3) * 64;

  __shared__ unsigned short As[2][16384];
  __shared__ unsigned short Bs[2][16384];

  const int rowb = tid >> 3;
  const int sw = (((tid & 7) ^ (rowb & 7)) << 4);
  const int hbase = hoff[e] + mblk * 256;
  const char* asrc[4]; int astep[4];
  const char* bsrc[4];
#pragma unroll
  for (int i = 0; i < 4; ++i) {
    asrc[i] = (const char*)(h + (size_t)(hbase + i * 64 + rowb) * F_DIM + kofs) + sw;
    astep[i] = 128;
    bsrc[i] = (const char*)(w2t + ((size_t)e * D_DIM + nblk * 256 + i * 64 + rowb) * F_DIM + kofs) + sw;
  }

  f32x4 acc[8][4];
#pragma unroll
  for (int i = 0; i < 8; ++i)
#pragma unroll
    for (int j = 0; j < 4; ++j) acc[i][j] = f32x4{0.f, 0.f, 0.f, 0.f};

  KLOOP2(32);

#pragma unroll
  for (int mf = 0; mf < 8; ++mf) {
#pragma unroll
    for (int r = 0; r < 4; ++r) {
      int slot = mblk * 256 + wm + mf * 16 + ((lane >> 4) << 2) + r;
      if (slot < c) {
        int tok = list[e * N_TOK + slot];
        float cf = coef[e * N_TOK + slot];
#pragma unroll
        for (int nf = 0; nf < 4; ++nf) {
          int col = nblk * 256 + wn + nf * 16 + (lane & 15);
          unsafeAtomicAdd(&out[(size_t)tok * D_DIM + col], cf * acc[mf][nf][r]);
        }
      }
    }
  }
}

// ------------------------------------------------- fallback (round-1) GEMMs --
__global__ __launch_bounds__(256) void gemm1_v1(
    const float* __restrict__ x, const float* __restrict__ w1,
    const int* __restrict__ cnt, const int* __restrict__ hoff,
    const int* __restrict__ list, unsigned short* __restrict__ h) {
  const int e = blockIdx.z, mblk = blockIdx.y, nblk = blockIdx.x;
  const int c = cnt[e];
  if (mblk * 128 >= c) return;
  const int tid = threadIdx.x, lane = tid & 63, wave = tid >> 6;
  const int wm = (wave >> 1) * 64, wn = (wave & 1) * 64;

  __shared__ unsigned short At[128 * 64];
  __shared__ unsigned short Bt[128 * 64];
  __shared__ int toks[128];
  if (tid < 128) {
    int slot = mblk * 128 + tid;
    toks[tid] = (slot < c) ? list[e * N_TOK + slot] : -1;
  }
  __syncthreads();

  f32x4 acc[4][4];
#pragma unroll
  for (int i = 0; i < 4; ++i)
#pragma unroll
    for (int j = 0; j < 4; ++j) acc[i][j] = f32x4{0.f, 0.f, 0.f, 0.f};

  const float* w1e = w1 + (size_t)e * D_DIM * F_DIM;
  for (int kc = 0; kc < 16; ++kc) {
    __syncthreads();
#pragma unroll
    for (int it = 0; it < 8; ++it) {
      int lin = it * 256 + tid;
      int row = lin >> 4, c4 = lin & 15;
      int tok = toks[row];
      unsigned int lo = 0u, hi = 0u;
      if (tok >= 0) {
        float4v f = *(const float4v*)(x + (size_t)tok * D_DIM + kc * 64 + c4 * 4);
        lo = (unsigned int)f2bf(f.x) | ((unsigned int)f2bf(f.y) << 16);
        hi = (unsigned int)f2bf(f.z) | ((unsigned int)f2bf(f.w) << 16);
      }
      int byte = (row * 128 + c4 * 8) ^ ((row & 7) << 4);
      *(u32x2*)((char*)At + byte) = u32x2{lo, hi};
    }
#pragma unroll
    for (int it = 0; it < 16; ++it) {
      int lin = it * 256 + tid;
      int f_loc = lin & 127, dp = lin >> 7;
      int d = kc * 64 + dp * 2;
      const float* src = w1e + (size_t)d * F_DIM + nblk * 128 + f_loc;
      unsigned int pk = (unsigned int)f2bf(src[0]) |
                        ((unsigned int)f2bf(src[F_DIM]) << 16);
      int byte = (f_loc * 128 + dp * 4) ^ ((f_loc & 7) << 4);
      *(unsigned int*)((char*)Bt + byte) = pk;
    }
    __syncthreads();
#pragma unroll
    for (int ks = 0; ks < 2; ++ks) {
      short8 af[4], bb[4];
#pragma unroll
      for (int mf = 0; mf < 4; ++mf) af[mf] = ld_frag(At, wm + mf * 16, ks * 32, lane);
#pragma unroll
      for (int nf = 0; nf < 4; ++nf) bb[nf] = ld_frag(Bt, wn + nf * 16, ks * 32, lane);
#pragma unroll
      for (int mf = 0; mf < 4; ++mf)
#pragma unroll
        for (int nf = 0; nf < 4; ++nf)
          acc[mf][nf] = __builtin_amdgcn_mfma_f32_16x16x32_bf16(
              af[mf], bb[nf], acc[mf][nf], 0, 0, 0);
    }
  }

  const int hbase = hoff[e] + mblk * 128;
#pragma unroll
  for (int mf = 0; mf < 4; ++mf)
#pragma unroll
    for (int nf = 0; nf < 4; ++nf)
#pragma unroll
      for (int r = 0; r < 4; ++r) {
        float v = acc[mf][nf][r];
        v = v / (1.f + __expf(-v));
        int row = wm + mf * 16 + ((lane >> 4) << 2) + r;
        int col = nblk * 128 + wn + nf * 16 + (lane & 15);
        h[(size_t)(hbase + row) * F_DIM + col] = f2bf(v);
      }
}

__global__ __launch_bounds__(256) void gemm2_v1(
    const unsigned short* __restrict__ h, const float* __restrict__ w2,
    const int* __restrict__ cnt, const int* __restrict__ hoff,
    const int* __restrict__ list, const float* __restrict__ coef,
    float* __restrict__ out) {
  const int e = blockIdx.z, mblk = blockIdx.y, nblk = blockIdx.x;
  const int c = cnt[e];
  if (mblk * 128 >= c) return;
  const int tid = threadIdx.x, lane = tid & 63, wave = tid >> 6;
  const int wm = (wave >> 1) * 64, wn = (wave & 1) * 64;

  __shared__ unsigned short At[128 * 64];
  __shared__ unsigned short Bt[128 * 64];

  f32x4 acc[4][4];
#pragma unroll
  for (int i = 0; i < 4; ++i)
#pragma unroll
    for (int j = 0; j < 4; ++j) acc[i][j] = f32x4{0.f, 0.f, 0.f, 0.f};

  const int hbase = hoff[e] + mblk * 128;
  const float* w2e = w2 + (size_t)e * F_DIM * D_DIM;
  for (int kc = 0; kc < 64; ++kc) {
    __syncthreads();
#pragma unroll
    for (int it = 0; it < 8; ++it) {
      int lin = it * 256 + tid;
      int row = lin >> 4, c4 = lin & 15;
      u32x2 v = *(const u32x2*)(h + (size_t)(hbase + row) * F_DIM + kc * 64 + c4 * 4);
      int byte = (row * 128 + c4 * 8) ^ ((row & 7) << 4);
      *(u32x2*)((char*)At + byte) = v;
    }
#pragma unroll
    for (int it = 0; it < 16; ++it) {
      int lin = it * 256 + tid;
      int dcol = lin & 127, kp = lin >> 7;
      int k = kc * 64 + kp * 2;
      const float* src = w2e + (size_t)k * D_DIM + nblk * 128 + dcol;
      unsigned int pk = (unsigned int)f2bf(src[0]) |
                        ((unsigned int)f2bf(src[D_DIM]) << 16);
      int byte = (dcol * 128 + kp * 4) ^ ((dcol & 7) << 4);
      *(unsigned int*)((char*)Bt + byte) = pk;
    }
    __syncthreads();
#pragma unroll
    for (int ks = 0; ks < 2; ++ks) {
      short8 af[4], bb[4];
#pragma unroll
      for (int mf = 0; mf < 4; ++mf) af[mf] = ld_frag(At, wm + mf * 16, ks * 32, lane);
#pragma unroll
      for (int nf = 0; nf < 4; ++nf) bb[nf] = ld_frag(Bt, wn + nf * 16, ks * 32, lane);
#pragma unroll
      for (int mf = 0; mf < 4; ++mf)
#pragma unroll
        for (int nf = 0; nf < 4; ++nf)
          acc[mf][nf] = __builtin_amdgcn_mfma_f32_16x16x32_bf16(
              af[mf], bb[nf], acc[mf][nf], 0, 0, 0);
    }
  }

#pragma unroll
  for (int mf = 0; mf < 4; ++mf) {
#pragma unroll
    for (int r = 0; r < 4; ++r) {
      int slot = mblk * 128 + wm + mf * 16 + ((lane >> 4) << 2) + r;
      if (slot < c) {
        int tok = list[e * N_TOK + slot];
        float cf = coef[e * N_TOK + slot];
#pragma unroll
        for (int nf = 0; nf < 4; ++nf) {
          int col = nblk * 128 + wn + nf * 16 + (lane & 15);
          unsafeAtomicAdd(&out[(size_t)tok * D_DIM + col], cf * acc[mf][nf][r]);
        }
      }
    }
  }
}

// ------------------------------------------------------------------ launch --
extern "C" void kernel_launch(void* const* d_in, const int* in_sizes, int n_in,
                              void* d_out, int out_size, void* d_ws, size_t ws_size,
                              hipStream_t stream) {
  const float* x = (const float*)d_in[0];
  const float* gw = (const float*)d_in[1];
  const float* w1 = (const float*)d_in[2];
  const float* w2 = (const float*)d_in[3];
  float* out = (float*)d_out;
  char* ws = (char*)d_ws;

  int* cnt = (int*)(ws + CNT_OFF);
  int* hoff = (int*)(ws + HOFF_OFF);
  int* nmb = (int*)(ws + NMB_OFF);
  int* mbe = (int*)(ws + MBE_OFF);
  int* mbb = (int*)(ws + MBB_OFF);
  float* psum = (float*)(ws + PSUM_OFF);
  int* list = (int*)(ws + LIST_OFF);
  float* coef = (float*)(ws + COEF_OFF);
  unsigned short* xbf = (unsigned short*)(ws + XBF_OFF);

  const bool full = (ws_size >= FULL_WS);

  hipMemsetAsync(d_ws, 0, PSUM_OFF + 2048 * 8 * 4, stream);
  hipMemsetAsync(d_out, 0, (size_t)out_size * 4, stream);

  router_kernel<<<2048, 256, 0, stream>>>(x, gw, cnt, list, coef, psum, xbf);
  prefix_kernel<<<1, 64, 0, stream>>>(cnt, hoff, mbe, mbb, nmb, full ? 256 : 128);
  kl_kernel<<<1, 256, 0, stream>>>(psum, out + 8388608);

  if (full) {
    unsigned short* w1t = (unsigned short*)(ws + W1T_OFF);
    unsigned short* w2t = (unsigned short*)(ws + W2T_OFF);
    unsigned short* h = (unsigned short*)(ws + H2_OFF);
    const unsigned short* zpage = (const unsigned short*)(ws + ZPG_OFF);

    wtrans_kernel<<<dim3(64, 16, 8), 256, 0, stream>>>(w1, w1t, 1024, 4096);
    wtrans_kernel<<<dim3(16, 64, 8), 256, 0, stream>>>(w2, w2t, 4096, 1024);
    gemm1_v8<<<dim3(MB_MAX, 16), 512, 0, stream>>>(xbf, w1t, cnt, hoff, mbe, mbb,
                                                   nmb, list, zpage, h);
    gemm2_v8<<<dim3(MB_MAX, 8), 512, 0, stream>>>(h, w2t, cnt, hoff, mbe, mbb,
                                                  nmb, list, coef, out);
  } else {
    unsigned short* h = (unsigned short*)(ws + H1_OFF);
    gemm1_v1<<<dim3(32, 64, 8), 256, 0, stream>>>(x, w1, cnt, hoff, list, h);
    gemm2_v1<<<dim3(8, 64, 8), 256, 0, stream>>>(h, w2, cnt, hoff, list, coef, out);
  }
}